// Round 12
// baseline (130.054 us; speedup 1.0000x reference)
//
#include <hip/hip_runtime.h>
#include <stdint.h>

#define N_ACT 100000
#define B_ROWS 2048
#define NPAD 100352          // 3136 * 32
#define NC16 (NPAD / 16)     // 6272
#define NC32 (NPAD / 32)     // 3136
#define MC16 (B_ROWS / 16)   // 128
#define NSPLIT 448           // %8==0 -> same-slice blocks share bid%8 (one XCD)
#define CPB (NC32 / NSPLIT)  // 7 n-chunks per block
#define MBLK (B_ROWS / 256)  // 8 m-blocks
#define GRID (MBLK * NSPLIT) // 3584

#define SCALE 1.2011224087864498f   // sqrt(log2(e)); z'.x' = log2e * z.x
#define THRESH -40.5f               // skip tile if max log2(P) below this

typedef __attribute__((ext_vector_type(8))) short bf16x8;
typedef __attribute__((ext_vector_type(4))) float f32x4;

#if __has_builtin(__builtin_amdgcn_exp2f)
#define EXP2(x) __builtin_amdgcn_exp2f(x)
#else
#define EXP2(x) exp2f(x)
#endif

static __device__ __forceinline__ unsigned pack_hi16(unsigned u1, unsigned u0) {
#if __has_builtin(__builtin_amdgcn_perm)
  return __builtin_amdgcn_perm(u1, u0, 0x07060302u);
#else
  return (u1 & 0xffff0000u) | (u0 >> 16);
#endif
}

static __device__ __forceinline__ unsigned short f2bf(float f) {
  unsigned u = __float_as_uint(f);
  u += 0x7fffu + ((u >> 16) & 1u);
  return (unsigned short)(u >> 16);
}
static __device__ __forceinline__ float bf2f(unsigned short h) {
  return __uint_as_float(((unsigned)h) << 16);
}

static __device__ __forceinline__ void pack_wave(
    const float* __restrict__ src, int nvalid, int wid, int lane,
    bf16x8* __restrict__ dh, bf16x8* __restrict__ dl, float* __restrict__ sq) {
  int q = lane >> 4, c = lane & 15;
  int row = wid * 16 + c;
  float v[2][8];
  if (row < nvalid) {
    const float4* p0 = (const float4*)(src + row * 64 + q * 8);
    const float4* p1 = (const float4*)(src + row * 64 + 32 + q * 8);
    float4 a = p0[0], b = p0[1], e = p1[0], f = p1[1];
    v[0][0] = a.x * SCALE; v[0][1] = a.y * SCALE; v[0][2] = a.z * SCALE; v[0][3] = a.w * SCALE;
    v[0][4] = b.x * SCALE; v[0][5] = b.y * SCALE; v[0][6] = b.z * SCALE; v[0][7] = b.w * SCALE;
    v[1][0] = e.x * SCALE; v[1][1] = e.y * SCALE; v[1][2] = e.z * SCALE; v[1][3] = e.w * SCALE;
    v[1][4] = f.x * SCALE; v[1][5] = f.y * SCALE; v[1][6] = f.z * SCALE; v[1][7] = f.w * SCALE;
  } else {
#pragma unroll
    for (int kh = 0; kh < 2; ++kh)
#pragma unroll
      for (int j = 0; j < 8; ++j) v[kh][j] = 0.f;
  }
  float s = 0.f;
#pragma unroll
  for (int kh = 0; kh < 2; ++kh)
#pragma unroll
    for (int j = 0; j < 8; ++j) s += v[kh][j] * v[kh][j];
  s += __shfl_xor(s, 16, 64);
  s += __shfl_xor(s, 32, 64);
#pragma unroll
  for (int kh = 0; kh < 2; ++kh) {
    bf16x8 hv, lv;
#pragma unroll
    for (int j = 0; j < 8; ++j) {
      unsigned short h = f2bf(v[kh][j]);
      hv[j] = (short)h;
      lv[j] = (short)f2bf(v[kh][j] - bf2f(h));
    }
    dh[(wid * 2 + kh) * 64 + lane] = hv;
    dl[(wid * 2 + kh) * 64 + lane] = lv;
  }
  if (lane < 16) sq[wid * 16 + c] = (row < nvalid) ? (-0.5f * s) : -100000.f;
}

static __device__ __forceinline__ void alpha_wave(
    const float* __restrict__ alpha, int nc2, int lane,
    bf16x8* __restrict__ dh, bf16x8* __restrict__ dl) {
  int f = lane & 15, q = lane >> 4;
  bf16x8 hv, lv;
#pragma unroll
  for (int j = 0; j < 8; ++j) {
    int n = nc2 * 32 + q * 8 + j;
    float v = (n < N_ACT) ? alpha[n * 16 + f] : 0.f;
    unsigned short h = f2bf(v);
    hv[j] = (short)h;
    lv[j] = (short)f2bf(v - bf2f(h));
  }
  dh[nc2 * 64 + lane] = hv;
  dl[nc2 * 64 + lane] = lv;
}

// prep + output zeroing fused (one dispatch fewer; prep completes before
// rbf_main by stream order, so atomics see a zeroed out buffer).
#define PREP_WAVES (NC16 + MC16 + NC32)   // 9536
#define ZERO_WAVES 128                    // 8192 threads x float4 = 32768 f32
__global__ void prep_all(const float* __restrict__ z, const float* __restrict__ dataset,
                         const float* __restrict__ alpha,
                         bf16x8* __restrict__ xph, bf16x8* __restrict__ xpl,
                         bf16x8* __restrict__ zph, bf16x8* __restrict__ zpl,
                         bf16x8* __restrict__ aph, bf16x8* __restrict__ apl,
                         float* __restrict__ xs2, float* __restrict__ zs2,
                         float* __restrict__ out) {
  int gw = (blockIdx.x * 256 + threadIdx.x) >> 6;
  int lane = threadIdx.x & 63;
  if (gw < NC16) {
    pack_wave(dataset, N_ACT, gw, lane, xph, xpl, xs2);
  } else if (gw < NC16 + MC16) {
    pack_wave(z, B_ROWS, gw - NC16, lane, zph, zpl, zs2);
  } else if (gw < PREP_WAVES) {
    alpha_wave(alpha, gw - (NC16 + MC16), lane, aph, apl);
  } else {
    int idx = (gw - PREP_WAVES) * 64 + lane;  // 0..8191
    ((float4*)out)[idx] = (float4){0.f, 0.f, 0.f, 0.f};
  }
}

// ---- fused main: x_hi slice in LDS (28.7 KB) + half-height P tile (10.2 KB)
// -> 39.8 KB total -> 4 blocks/CU (was 3 at 50 KB). Rare path processes mi in
// two halves through the shared P tile; wave-internal DS ordering (in-order
// per wave) makes the write->read->overwrite sequence safe without barriers.
// waves_per_eu(4,4): VGPR cap 128 — common path fits (~115); rare path may
// spill a few cold regs (5% of visits).
__global__ __launch_bounds__(256)
__attribute__((amdgpu_waves_per_eu(4, 4))) void rbf_main(
    const bf16x8* __restrict__ xph, const bf16x8* __restrict__ xpl,
    const bf16x8* __restrict__ aph, const bf16x8* __restrict__ apl,
    const bf16x8* __restrict__ zph, const bf16x8* __restrict__ zpl,
    const float* __restrict__ xs2, const float* __restrict__ zs2,
    float* __restrict__ out) {
  __shared__ __align__(16) unsigned short xlds[CPB * 2048];  // 28,672 B
  __shared__ __align__(16) float xs2l[CPB * 32];             // 896 B
  __shared__ __align__(16) unsigned short plds[4][32][40];   // 10,240 B
  const int tid = threadIdx.x;
  const int lane = tid & 63;
  const int w = tid >> 6;
  const int q = lane >> 4, c = lane & 15;
  const int bid = blockIdx.x;
  const int yb = bid % NSPLIT;       // 448%8==0 -> same-slice blocks on one XCD
  const int mbi = bid / NSPLIT;
  const int mb = mbi * 256 + w * 64;
  const int mc0 = mb >> 4;
  const int nc2_0 = yb * CPB;

  // stage x_hi slice (CPB * 4 KB contiguous) + xs2 slice
  {
    const bf16x8* gx = xph + nc2_0 * 256;  // 256 bf16x8 per nc2
#pragma unroll
    for (int it = 0; it < CPB; ++it)
      *(bf16x8*)(xlds + it * 2048 + tid * 8) = gx[it * 256 + tid];
    if (tid < CPB * 32) xs2l[tid] = xs2[nc2_0 * 32 + tid];
  }

  bf16x8 zfh[4][2];
#pragma unroll
  for (int mi = 0; mi < 4; ++mi)
#pragma unroll
    for (int kh = 0; kh < 2; ++kh)
      zfh[mi][kh] = zph[((mc0 + mi) * 2 + kh) * 64 + lane];

  float zq[4];
#pragma unroll
  for (int mi = 0; mi < 4; ++mi) zq[mi] = zs2[mb + mi * 16 + c];

  f32x4 oacc[4];
#pragma unroll
  for (int mi = 0; mi < 4; ++mi) oacc[mi] = (f32x4){0.f, 0.f, 0.f, 0.f};
  int hit = 0;

  unsigned* pwbase = (unsigned*)plds + (w * 32 + c) * 20 + q * 2;
  const unsigned short* prdb = (unsigned short*)plds + (w * 32 + c) * 40 + q * 8;
  const bf16x8* zplb = zpl + mc0 * 2 * 64 + lane;

  __syncthreads();

#pragma unroll
  for (int it = 0; it < CPB; ++it) {
    const int nc2 = nc2_0 + it;
    bf16x8 xf[2][2];
#pragma unroll
    for (int nh = 0; nh < 2; ++nh)
#pragma unroll
      for (int kh = 0; kh < 2; ++kh)
        xf[nh][kh] = *(const bf16x8*)(xlds + it * 2048 + (nh * 2 + kh) * 512 + lane * 8);
    f32x4 xq[2];
#pragma unroll
    for (int nh = 0; nh < 2; ++nh)
      xq[nh] = *(const f32x4*)(xs2l + it * 32 + nh * 16 + q * 4);

    // S_hh = x_hi.z_hi^T - 0.5||x||^2 (z-norm folded into vote via zq)
    f32x4 acc[4][2];
#pragma unroll
    for (int mi = 0; mi < 4; ++mi)
#pragma unroll
      for (int nh = 0; nh < 2; ++nh) {
        f32x4 a = __builtin_amdgcn_mfma_f32_16x16x32_bf16(xf[nh][0], zfh[mi][0], xq[nh], 0, 0, 0);
        acc[mi][nh] = __builtin_amdgcn_mfma_f32_16x16x32_bf16(xf[nh][1], zfh[mi][1], a, 0, 0, 0);
      }

    float d = -1e30f;
#pragma unroll
    for (int mi = 0; mi < 4; ++mi) {
      float mx = fmaxf(fmaxf(acc[mi][0][0], acc[mi][0][1]),
                       fmaxf(acc[mi][0][2], acc[mi][0][3]));
      mx = fmaxf(mx, fmaxf(fmaxf(acc[mi][1][0], acc[mi][1][1]),
                           fmaxf(acc[mi][1][2], acc[mi][1][3])));
      d = fmaxf(d, mx + zq[mi]);
    }
    if (!__any(d > THRESH)) continue;  // ~95% of tiles

    // ---- rare path: refine + exp2 + half-height P tile + P@alpha ----
    hit = 1;
    bf16x8 xl[2][2];
#pragma unroll
    for (int nh = 0; nh < 2; ++nh)
#pragma unroll
      for (int kh = 0; kh < 2; ++kh)
        xl[nh][kh] = xpl[(nc2 * 4 + nh * 2 + kh) * 64 + lane];
    bf16x8 ah = aph[nc2 * 64 + lane];
    bf16x8 al = apl[nc2 * 64 + lane];

#pragma unroll
    for (int h = 0; h < 2; ++h) {
#pragma unroll
      for (int mi2 = 0; mi2 < 2; ++mi2) {
        const int mi = h * 2 + mi2;
        bf16x8 zl0 = zplb[mi * 128];
        bf16x8 zl1 = zplb[mi * 128 + 64];
#pragma unroll
        for (int nh = 0; nh < 2; ++nh) {
          f32x4 a = acc[mi][nh];
          a = __builtin_amdgcn_mfma_f32_16x16x32_bf16(xf[nh][0], zl0, a, 0, 0, 0);
          a = __builtin_amdgcn_mfma_f32_16x16x32_bf16(xl[nh][0], zfh[mi][0], a, 0, 0, 0);
          a = __builtin_amdgcn_mfma_f32_16x16x32_bf16(xf[nh][1], zl1, a, 0, 0, 0);
          a = __builtin_amdgcn_mfma_f32_16x16x32_bf16(xl[nh][1], zfh[mi][1], a, 0, 0, 0);
          // P = 2^(S' + zq) — z-factor applied exactly once here
#pragma unroll
          for (int p = 0; p < 2; ++p) {
            float e0 = EXP2(a[2 * p] + zq[mi]);
            float e1 = EXP2(a[2 * p + 1] + zq[mi]);
            unsigned u0 = __float_as_uint(e0) + 0x8000u;
            unsigned u1 = __float_as_uint(e1) + 0x8000u;
            pwbase[(mi2 * 16) * 20 + nh * 8 + p] = pack_hi16(u1, u0);
          }
        }
      }
#pragma unroll
      for (int mi2 = 0; mi2 < 2; ++mi2) {
        const int mi = h * 2 + mi2;
        bf16x8 ph = *(const bf16x8*)(prdb + mi2 * 640);
        oacc[mi] = __builtin_amdgcn_mfma_f32_16x16x32_bf16(ph, ah, oacc[mi], 0, 0, 0);
        oacc[mi] = __builtin_amdgcn_mfma_f32_16x16x32_bf16(ph, al, oacc[mi], 0, 0, 0);
      }
    }
  }

  if (hit) {  // waves with no rare tile contribute nothing
#pragma unroll
    for (int mi = 0; mi < 4; ++mi)
#pragma unroll
      for (int r = 0; r < 4; ++r) {
        int m = mb + mi * 16 + q * 4 + r;
        atomicAdd(&out[m * 16 + c], oacc[mi][r]);
      }
  }
}

extern "C" void kernel_launch(void* const* d_in, const int* in_sizes, int n_in,
                              void* d_out, int out_size, void* d_ws, size_t ws_size,
                              hipStream_t stream) {
  const float* z = (const float*)d_in[0];
  const float* dataset = (const float*)d_in[1];
  const float* alpha = (const float*)d_in[2];
  float* out = (float*)d_out;
  char* ws = (char*)d_ws;

  bf16x8* xph = (bf16x8*)ws;                       // 12,845,056
  bf16x8* xpl = xph + NC16 * 2 * 64;               // -> 25,690,112
  bf16x8* aph = (bf16x8*)(ws + 25690112);          // 3,211,264
  bf16x8* apl = aph + NC32 * 64;                   // -> 32,112,640
  bf16x8* zph = (bf16x8*)(ws + 32112640);          // 262,144
  bf16x8* zpl = zph + MC16 * 2 * 64;               // -> 32,636,928
  float* xs2 = (float*)(ws + 32636928);            // NPAD floats -> 33,038,336
  float* zs2 = (float*)(ws + 33038336);            // 2048 floats -> 33,046,528

  int total_waves = PREP_WAVES + ZERO_WAVES;       // 9664
  prep_all<<<dim3(total_waves / 4), dim3(256), 0, stream>>>(
      z, dataset, alpha, xph, xpl, zph, zpl, aph, apl, xs2, zs2, out);
  rbf_main<<<dim3(GRID), dim3(256), 0, stream>>>(
      xph, xpl, aph, apl, zph, zpl, xs2, zs2, out);
}

// Round 13
// 116.804 us; speedup vs baseline: 1.1134x; 1.1134x over previous
//
#include <hip/hip_runtime.h>
#include <stdint.h>

#define N_ACT 100000
#define B_ROWS 2048
#define NPAD 100352          // 3136 * 32
#define NC16 (NPAD / 16)     // 6272
#define NC32 (NPAD / 32)     // 3136
#define MC16 (B_ROWS / 16)   // 128
#define NSPLIT 448           // %8==0 -> same-slice blocks share bid%8 (one XCD)
#define CPB (NC32 / NSPLIT)  // 7 n-chunks per block
#define MBLK (B_ROWS / 256)  // 8 m-blocks
#define GRID (MBLK * NSPLIT) // 3584

#define SCALE 1.2011224087864498f   // sqrt(log2(e)); z'.x' = log2e * z.x
#define THRESH -40.5f               // skip tile if max log2(P) below this

typedef __attribute__((ext_vector_type(8))) short bf16x8;
typedef __attribute__((ext_vector_type(4))) float f32x4;

#if __has_builtin(__builtin_amdgcn_exp2f)
#define EXP2(x) __builtin_amdgcn_exp2f(x)
#else
#define EXP2(x) exp2f(x)
#endif

static __device__ __forceinline__ unsigned pack_hi16(unsigned u1, unsigned u0) {
#if __has_builtin(__builtin_amdgcn_perm)
  return __builtin_amdgcn_perm(u1, u0, 0x07060302u);
#else
  return (u1 & 0xffff0000u) | (u0 >> 16);
#endif
}

static __device__ __forceinline__ unsigned short f2bf(float f) {
  unsigned u = __float_as_uint(f);
  u += 0x7fffu + ((u >> 16) & 1u);
  return (unsigned short)(u >> 16);
}
static __device__ __forceinline__ float bf2f(unsigned short h) {
  return __uint_as_float(((unsigned)h) << 16);
}

static __device__ __forceinline__ void pack_wave(
    const float* __restrict__ src, int nvalid, int wid, int lane,
    bf16x8* __restrict__ dh, bf16x8* __restrict__ dl, float* __restrict__ sq) {
  int q = lane >> 4, c = lane & 15;
  int row = wid * 16 + c;
  float v[2][8];
  if (row < nvalid) {
    const float4* p0 = (const float4*)(src + row * 64 + q * 8);
    const float4* p1 = (const float4*)(src + row * 64 + 32 + q * 8);
    float4 a = p0[0], b = p0[1], e = p1[0], f = p1[1];
    v[0][0] = a.x * SCALE; v[0][1] = a.y * SCALE; v[0][2] = a.z * SCALE; v[0][3] = a.w * SCALE;
    v[0][4] = b.x * SCALE; v[0][5] = b.y * SCALE; v[0][6] = b.z * SCALE; v[0][7] = b.w * SCALE;
    v[1][0] = e.x * SCALE; v[1][1] = e.y * SCALE; v[1][2] = e.z * SCALE; v[1][3] = e.w * SCALE;
    v[1][4] = f.x * SCALE; v[1][5] = f.y * SCALE; v[1][6] = f.z * SCALE; v[1][7] = f.w * SCALE;
  } else {
#pragma unroll
    for (int kh = 0; kh < 2; ++kh)
#pragma unroll
      for (int j = 0; j < 8; ++j) v[kh][j] = 0.f;
  }
  float s = 0.f;
#pragma unroll
  for (int kh = 0; kh < 2; ++kh)
#pragma unroll
    for (int j = 0; j < 8; ++j) s += v[kh][j] * v[kh][j];
  s += __shfl_xor(s, 16, 64);
  s += __shfl_xor(s, 32, 64);
#pragma unroll
  for (int kh = 0; kh < 2; ++kh) {
    bf16x8 hv, lv;
#pragma unroll
    for (int j = 0; j < 8; ++j) {
      unsigned short h = f2bf(v[kh][j]);
      hv[j] = (short)h;
      lv[j] = (short)f2bf(v[kh][j] - bf2f(h));
    }
    dh[(wid * 2 + kh) * 64 + lane] = hv;
    dl[(wid * 2 + kh) * 64 + lane] = lv;
  }
  if (lane < 16) sq[wid * 16 + c] = (row < nvalid) ? (-0.5f * s) : -100000.f;
}

static __device__ __forceinline__ void alpha_wave(
    const float* __restrict__ alpha, int nc2, int lane,
    bf16x8* __restrict__ dh, bf16x8* __restrict__ dl) {
  int f = lane & 15, q = lane >> 4;
  bf16x8 hv, lv;
#pragma unroll
  for (int j = 0; j < 8; ++j) {
    int n = nc2 * 32 + q * 8 + j;
    float v = (n < N_ACT) ? alpha[n * 16 + f] : 0.f;
    unsigned short h = f2bf(v);
    hv[j] = (short)h;
    lv[j] = (short)f2bf(v - bf2f(h));
  }
  dh[nc2 * 64 + lane] = hv;
  dl[nc2 * 64 + lane] = lv;
}

// prep + output zeroing fused (kept from R12 — one dispatch fewer).
#define PREP_WAVES (NC16 + MC16 + NC32)   // 9536
#define ZERO_WAVES 128                    // 8192 threads x float4 = 32768 f32
__global__ void prep_all(const float* __restrict__ z, const float* __restrict__ dataset,
                         const float* __restrict__ alpha,
                         bf16x8* __restrict__ xph, bf16x8* __restrict__ xpl,
                         bf16x8* __restrict__ zph, bf16x8* __restrict__ zpl,
                         bf16x8* __restrict__ aph, bf16x8* __restrict__ apl,
                         float* __restrict__ xs2, float* __restrict__ zs2,
                         float* __restrict__ out) {
  int gw = (blockIdx.x * 256 + threadIdx.x) >> 6;
  int lane = threadIdx.x & 63;
  if (gw < NC16) {
    pack_wave(dataset, N_ACT, gw, lane, xph, xpl, xs2);
  } else if (gw < NC16 + MC16) {
    pack_wave(z, B_ROWS, gw - NC16, lane, zph, zpl, zs2);
  } else if (gw < PREP_WAVES) {
    alpha_wave(alpha, gw - (NC16 + MC16), lane, aph, apl);
  } else {
    int idx = (gw - PREP_WAVES) * 64 + lane;  // 0..8191
    ((float4*)out)[idx] = (float4){0.f, 0.f, 0.f, 0.f};
  }
}

// ---- fused main: EXACT R11 configuration (best measured: 118.5 us total).
// x_hi slice in LDS (28.7 KB) + full-height P tile (20.5 KB) = 50 KB ->
// 3 blocks/CU; waves_per_eu(3,3) -> VGPR budget ~170 covers the ~140-reg
// rare-path peak with NO spills. R12's half-height-P + (4,4) variant spilled
// (VGPR_Count 64, WRITE_SIZE 79 MB of scratch, main 55 us) — register
// pressure beats LDS occupancy here; do not shrink the P tile.
__global__ __launch_bounds__(256)
__attribute__((amdgpu_waves_per_eu(3, 3))) void rbf_main(
    const bf16x8* __restrict__ xph, const bf16x8* __restrict__ xpl,
    const bf16x8* __restrict__ aph, const bf16x8* __restrict__ apl,
    const bf16x8* __restrict__ zph, const bf16x8* __restrict__ zpl,
    const float* __restrict__ xs2, const float* __restrict__ zs2,
    float* __restrict__ out) {
  __shared__ __align__(16) unsigned short xlds[CPB * 2048];  // 28,672 B
  __shared__ __align__(16) float xs2l[CPB * 32];             // 896 B
  __shared__ __align__(16) unsigned short plds[4][64][40];   // 20,480 B
  const int tid = threadIdx.x;
  const int lane = tid & 63;
  const int w = tid >> 6;
  const int q = lane >> 4, c = lane & 15;
  const int bid = blockIdx.x;
  const int yb = bid % NSPLIT;       // 448%8==0 -> same-slice blocks on one XCD
  const int mbi = bid / NSPLIT;
  const int mb = mbi * 256 + w * 64;
  const int mc0 = mb >> 4;
  const int nc2_0 = yb * CPB;

  // stage x_hi slice (CPB * 4 KB contiguous) + xs2 slice
  {
    const bf16x8* gx = xph + nc2_0 * 256;  // 256 bf16x8 per nc2
#pragma unroll
    for (int it = 0; it < CPB; ++it)
      *(bf16x8*)(xlds + it * 2048 + tid * 8) = gx[it * 256 + tid];
    if (tid < CPB * 32) xs2l[tid] = xs2[nc2_0 * 32 + tid];
  }

  bf16x8 zfh[4][2];
#pragma unroll
  for (int mi = 0; mi < 4; ++mi)
#pragma unroll
    for (int kh = 0; kh < 2; ++kh)
      zfh[mi][kh] = zph[((mc0 + mi) * 2 + kh) * 64 + lane];

  float zq[4];
#pragma unroll
  for (int mi = 0; mi < 4; ++mi) zq[mi] = zs2[mb + mi * 16 + c];

  f32x4 oacc[4];
#pragma unroll
  for (int mi = 0; mi < 4; ++mi) oacc[mi] = (f32x4){0.f, 0.f, 0.f, 0.f};
  int hit = 0;

  unsigned* pwbase = (unsigned*)plds + (w * 64 + c) * 20 + q * 2;
  const unsigned short* prdb = (unsigned short*)plds + (w * 64 + c) * 40 + q * 8;
  const bf16x8* zplb = zpl + mc0 * 2 * 64 + lane;

  __syncthreads();

#pragma unroll
  for (int it = 0; it < CPB; ++it) {
    const int nc2 = nc2_0 + it;
    bf16x8 xf[2][2];
#pragma unroll
    for (int nh = 0; nh < 2; ++nh)
#pragma unroll
      for (int kh = 0; kh < 2; ++kh)
        xf[nh][kh] = *(const bf16x8*)(xlds + it * 2048 + (nh * 2 + kh) * 512 + lane * 8);
    f32x4 xq[2];
#pragma unroll
    for (int nh = 0; nh < 2; ++nh)
      xq[nh] = *(const f32x4*)(xs2l + it * 32 + nh * 16 + q * 4);

    // S_hh = x_hi.z_hi^T - 0.5||x||^2 (z-norm folded into vote via zq)
    f32x4 acc[4][2];
#pragma unroll
    for (int mi = 0; mi < 4; ++mi)
#pragma unroll
      for (int nh = 0; nh < 2; ++nh) {
        f32x4 a = __builtin_amdgcn_mfma_f32_16x16x32_bf16(xf[nh][0], zfh[mi][0], xq[nh], 0, 0, 0);
        acc[mi][nh] = __builtin_amdgcn_mfma_f32_16x16x32_bf16(xf[nh][1], zfh[mi][1], a, 0, 0, 0);
      }

    float d = -1e30f;
#pragma unroll
    for (int mi = 0; mi < 4; ++mi) {
      float mx = fmaxf(fmaxf(acc[mi][0][0], acc[mi][0][1]),
                       fmaxf(acc[mi][0][2], acc[mi][0][3]));
      mx = fmaxf(mx, fmaxf(fmaxf(acc[mi][1][0], acc[mi][1][1]),
                           fmaxf(acc[mi][1][2], acc[mi][1][3])));
      d = fmaxf(d, mx + zq[mi]);
    }
    if (!__any(d > THRESH)) continue;  // ~95% of tiles

    // ---- rare path: refine with cross lo terms, exp2, LDS P, P@alpha ----
    hit = 1;
    bf16x8 xl[2][2];
#pragma unroll
    for (int nh = 0; nh < 2; ++nh)
#pragma unroll
      for (int kh = 0; kh < 2; ++kh)
        xl[nh][kh] = xpl[(nc2 * 4 + nh * 2 + kh) * 64 + lane];

#pragma unroll
    for (int mi = 0; mi < 4; ++mi) {
      bf16x8 zl0 = zplb[mi * 128];
      bf16x8 zl1 = zplb[mi * 128 + 64];
#pragma unroll
      for (int nh = 0; nh < 2; ++nh) {
        f32x4 a = acc[mi][nh];
        a = __builtin_amdgcn_mfma_f32_16x16x32_bf16(xf[nh][0], zl0, a, 0, 0, 0);
        a = __builtin_amdgcn_mfma_f32_16x16x32_bf16(xl[nh][0], zfh[mi][0], a, 0, 0, 0);
        a = __builtin_amdgcn_mfma_f32_16x16x32_bf16(xf[nh][1], zl1, a, 0, 0, 0);
        a = __builtin_amdgcn_mfma_f32_16x16x32_bf16(xl[nh][1], zfh[mi][1], a, 0, 0, 0);
        // P = 2^(S' + zq) — z-factor applied exactly once here
#pragma unroll
        for (int p = 0; p < 2; ++p) {
          float e0 = EXP2(a[2 * p] + zq[mi]);
          float e1 = EXP2(a[2 * p + 1] + zq[mi]);
          unsigned u0 = __float_as_uint(e0) + 0x8000u;
          unsigned u1 = __float_as_uint(e1) + 0x8000u;
          pwbase[(mi * 16) * 20 + nh * 8 + p] = pack_hi16(u1, u0);
        }
      }
    }
    bf16x8 ah = aph[nc2 * 64 + lane];
    bf16x8 al = apl[nc2 * 64 + lane];
#pragma unroll
    for (int mi = 0; mi < 4; ++mi) {
      bf16x8 ph = *(const bf16x8*)(prdb + mi * 640);
      oacc[mi] = __builtin_amdgcn_mfma_f32_16x16x32_bf16(ph, ah, oacc[mi], 0, 0, 0);
      oacc[mi] = __builtin_amdgcn_mfma_f32_16x16x32_bf16(ph, al, oacc[mi], 0, 0, 0);
    }
  }

  if (hit) {  // waves with no rare tile contribute nothing
#pragma unroll
    for (int mi = 0; mi < 4; ++mi)
#pragma unroll
      for (int r = 0; r < 4; ++r) {
        int m = mb + mi * 16 + q * 4 + r;
        atomicAdd(&out[m * 16 + c], oacc[mi][r]);
      }
  }
}

extern "C" void kernel_launch(void* const* d_in, const int* in_sizes, int n_in,
                              void* d_out, int out_size, void* d_ws, size_t ws_size,
                              hipStream_t stream) {
  const float* z = (const float*)d_in[0];
  const float* dataset = (const float*)d_in[1];
  const float* alpha = (const float*)d_in[2];
  float* out = (float*)d_out;
  char* ws = (char*)d_ws;

  bf16x8* xph = (bf16x8*)ws;                       // 12,845,056
  bf16x8* xpl = xph + NC16 * 2 * 64;               // -> 25,690,112
  bf16x8* aph = (bf16x8*)(ws + 25690112);          // 3,211,264
  bf16x8* apl = aph + NC32 * 64;                   // -> 32,112,640
  bf16x8* zph = (bf16x8*)(ws + 32112640);          // 262,144
  bf16x8* zpl = zph + MC16 * 2 * 64;               // -> 32,636,928
  float* xs2 = (float*)(ws + 32636928);            // NPAD floats -> 33,038,336
  float* zs2 = (float*)(ws + 33038336);            // 2048 floats -> 33,046,528

  int total_waves = PREP_WAVES + ZERO_WAVES;       // 9664
  prep_all<<<dim3(total_waves / 4), dim3(256), 0, stream>>>(
      z, dataset, alpha, xph, xpl, zph, zpl, aph, apl, xs2, zs2, out);
  rbf_main<<<dim3(GRID), dim3(256), 0, stream>>>(
      xph, xpl, aph, apl, zph, zpl, xs2, zs2, out);
}

// Round 14
// 114.787 us; speedup vs baseline: 1.1330x; 1.0176x over previous
//
#include <hip/hip_runtime.h>
#include <stdint.h>

#define N_ACT 100000
#define B_ROWS 2048
#define NPAD 100352          // 3136 * 32
#define NC16 (NPAD / 16)     // 6272
#define NC32 (NPAD / 32)     // 3136
#define MC16 (B_ROWS / 16)   // 128
#define NSPLIT 448           // %8==0 -> same-slice blocks share bid%8 (one XCD)
#define CPB (NC32 / NSPLIT)  // 7 n-chunks per block
#define MBLK (B_ROWS / 256)  // 8 m-blocks
#define GRID (MBLK * NSPLIT) // 3584

#define SCALE 1.2011224087864498f   // sqrt(log2(e)); z'.x' = log2e * z.x
#define THRESH -40.5f               // skip tile if max log2(P) below this

typedef __attribute__((ext_vector_type(8))) short bf16x8;
typedef __attribute__((ext_vector_type(4))) float f32x4;

#if __has_builtin(__builtin_amdgcn_exp2f)
#define EXP2(x) __builtin_amdgcn_exp2f(x)
#else
#define EXP2(x) exp2f(x)
#endif

static __device__ __forceinline__ unsigned pack_hi16(unsigned u1, unsigned u0) {
#if __has_builtin(__builtin_amdgcn_perm)
  return __builtin_amdgcn_perm(u1, u0, 0x07060302u);
#else
  return (u1 & 0xffff0000u) | (u0 >> 16);
#endif
}

static __device__ __forceinline__ unsigned short f2bf(float f) {
  unsigned u = __float_as_uint(f);
  u += 0x7fffu + ((u >> 16) & 1u);
  return (unsigned short)(u >> 16);
}
static __device__ __forceinline__ float bf2f(unsigned short h) {
  return __uint_as_float(((unsigned)h) << 16);
}

static __device__ __forceinline__ void pack_wave(
    const float* __restrict__ src, int nvalid, int wid, int lane,
    bf16x8* __restrict__ dh, bf16x8* __restrict__ dl, float* __restrict__ sq) {
  int q = lane >> 4, c = lane & 15;
  int row = wid * 16 + c;
  float v[2][8];
  if (row < nvalid) {
    const float4* p0 = (const float4*)(src + row * 64 + q * 8);
    const float4* p1 = (const float4*)(src + row * 64 + 32 + q * 8);
    float4 a = p0[0], b = p0[1], e = p1[0], f = p1[1];
    v[0][0] = a.x * SCALE; v[0][1] = a.y * SCALE; v[0][2] = a.z * SCALE; v[0][3] = a.w * SCALE;
    v[0][4] = b.x * SCALE; v[0][5] = b.y * SCALE; v[0][6] = b.z * SCALE; v[0][7] = b.w * SCALE;
    v[1][0] = e.x * SCALE; v[1][1] = e.y * SCALE; v[1][2] = e.z * SCALE; v[1][3] = e.w * SCALE;
    v[1][4] = f.x * SCALE; v[1][5] = f.y * SCALE; v[1][6] = f.z * SCALE; v[1][7] = f.w * SCALE;
  } else {
#pragma unroll
    for (int kh = 0; kh < 2; ++kh)
#pragma unroll
      for (int j = 0; j < 8; ++j) v[kh][j] = 0.f;
  }
  float s = 0.f;
#pragma unroll
  for (int kh = 0; kh < 2; ++kh)
#pragma unroll
    for (int j = 0; j < 8; ++j) s += v[kh][j] * v[kh][j];
  s += __shfl_xor(s, 16, 64);
  s += __shfl_xor(s, 32, 64);
#pragma unroll
  for (int kh = 0; kh < 2; ++kh) {
    bf16x8 hv, lv;
#pragma unroll
    for (int j = 0; j < 8; ++j) {
      unsigned short h = f2bf(v[kh][j]);
      hv[j] = (short)h;
      lv[j] = (short)f2bf(v[kh][j] - bf2f(h));
    }
    dh[(wid * 2 + kh) * 64 + lane] = hv;
    dl[(wid * 2 + kh) * 64 + lane] = lv;
  }
  if (lane < 16) sq[wid * 16 + c] = (row < nvalid) ? (-0.5f * s) : -100000.f;
}

// alpha: hi-only (alpha_lo contributes ~8e-14 to out, 5x margin available)
static __device__ __forceinline__ void alpha_wave(
    const float* __restrict__ alpha, int nc2, int lane,
    bf16x8* __restrict__ dh) {
  int f = lane & 15, q = lane >> 4;
  bf16x8 hv;
#pragma unroll
  for (int j = 0; j < 8; ++j) {
    int n = nc2 * 32 + q * 8 + j;
    float v = (n < N_ACT) ? alpha[n * 16 + f] : 0.f;
    hv[j] = (short)f2bf(v);
  }
  dh[nc2 * 64 + lane] = hv;
}

// prep + output zeroing fused (one dispatch fewer).
#define PREP_WAVES (NC16 + MC16 + NC32)   // 9536
#define ZERO_WAVES 128                    // 8192 threads x float4 = 32768 f32
__global__ void prep_all(const float* __restrict__ z, const float* __restrict__ dataset,
                         const float* __restrict__ alpha,
                         bf16x8* __restrict__ xph, bf16x8* __restrict__ xpl,
                         bf16x8* __restrict__ zph, bf16x8* __restrict__ zpl,
                         bf16x8* __restrict__ aph,
                         float* __restrict__ xs2, float* __restrict__ zs2,
                         float* __restrict__ out) {
  int gw = (blockIdx.x * 256 + threadIdx.x) >> 6;
  int lane = threadIdx.x & 63;
  if (gw < NC16) {
    pack_wave(dataset, N_ACT, gw, lane, xph, xpl, xs2);
  } else if (gw < NC16 + MC16) {
    pack_wave(z, B_ROWS, gw - NC16, lane, zph, zpl, zs2);
  } else if (gw < PREP_WAVES) {
    alpha_wave(alpha, gw - (NC16 + MC16), lane, aph);
  } else {
    int idx = (gw - PREP_WAVES) * 64 + lane;  // 0..8191
    ((float4*)out)[idx] = (float4){0.f, 0.f, 0.f, 0.f};
  }
}

// ---- fused main: R11/R13 configuration (empirical optimum) with alpha-lo
// dropped from the rare path. x_hi slice in LDS (28.7 KB) + full-height P
// tile (20.5 KB) = 50 KB -> 3 blocks/CU; waves_per_eu(3,3) -> VGPR budget
// ~170, no spills. Do NOT shrink the P tile or raise waves/EU: R12's
// half-height-P + (4,4) spilled (VGPR 64, 79 MB scratch writes, 55 us).
__global__ __launch_bounds__(256)
__attribute__((amdgpu_waves_per_eu(3, 3))) void rbf_main(
    const bf16x8* __restrict__ xph, const bf16x8* __restrict__ xpl,
    const bf16x8* __restrict__ aph,
    const bf16x8* __restrict__ zph, const bf16x8* __restrict__ zpl,
    const float* __restrict__ xs2, const float* __restrict__ zs2,
    float* __restrict__ out) {
  __shared__ __align__(16) unsigned short xlds[CPB * 2048];  // 28,672 B
  __shared__ __align__(16) float xs2l[CPB * 32];             // 896 B
  __shared__ __align__(16) unsigned short plds[4][64][40];   // 20,480 B
  const int tid = threadIdx.x;
  const int lane = tid & 63;
  const int w = tid >> 6;
  const int q = lane >> 4, c = lane & 15;
  const int bid = blockIdx.x;
  const int yb = bid % NSPLIT;       // 448%8==0 -> same-slice blocks on one XCD
  const int mbi = bid / NSPLIT;
  const int mb = mbi * 256 + w * 64;
  const int mc0 = mb >> 4;
  const int nc2_0 = yb * CPB;

  // stage x_hi slice (CPB * 4 KB contiguous) + xs2 slice
  {
    const bf16x8* gx = xph + nc2_0 * 256;  // 256 bf16x8 per nc2
#pragma unroll
    for (int it = 0; it < CPB; ++it)
      *(bf16x8*)(xlds + it * 2048 + tid * 8) = gx[it * 256 + tid];
    if (tid < CPB * 32) xs2l[tid] = xs2[nc2_0 * 32 + tid];
  }

  bf16x8 zfh[4][2];
#pragma unroll
  for (int mi = 0; mi < 4; ++mi)
#pragma unroll
    for (int kh = 0; kh < 2; ++kh)
      zfh[mi][kh] = zph[((mc0 + mi) * 2 + kh) * 64 + lane];

  float zq[4];
#pragma unroll
  for (int mi = 0; mi < 4; ++mi) zq[mi] = zs2[mb + mi * 16 + c];

  f32x4 oacc[4];
#pragma unroll
  for (int mi = 0; mi < 4; ++mi) oacc[mi] = (f32x4){0.f, 0.f, 0.f, 0.f};
  int hit = 0;

  unsigned* pwbase = (unsigned*)plds + (w * 64 + c) * 20 + q * 2;
  const unsigned short* prdb = (unsigned short*)plds + (w * 64 + c) * 40 + q * 8;
  const bf16x8* zplb = zpl + mc0 * 2 * 64 + lane;

  __syncthreads();

#pragma unroll
  for (int it = 0; it < CPB; ++it) {
    const int nc2 = nc2_0 + it;
    bf16x8 xf[2][2];
#pragma unroll
    for (int nh = 0; nh < 2; ++nh)
#pragma unroll
      for (int kh = 0; kh < 2; ++kh)
        xf[nh][kh] = *(const bf16x8*)(xlds + it * 2048 + (nh * 2 + kh) * 512 + lane * 8);
    f32x4 xq[2];
#pragma unroll
    for (int nh = 0; nh < 2; ++nh)
      xq[nh] = *(const f32x4*)(xs2l + it * 32 + nh * 16 + q * 4);

    // S_hh = x_hi.z_hi^T - 0.5||x||^2 (z-norm folded into vote via zq)
    f32x4 acc[4][2];
#pragma unroll
    for (int mi = 0; mi < 4; ++mi)
#pragma unroll
      for (int nh = 0; nh < 2; ++nh) {
        f32x4 a = __builtin_amdgcn_mfma_f32_16x16x32_bf16(xf[nh][0], zfh[mi][0], xq[nh], 0, 0, 0);
        acc[mi][nh] = __builtin_amdgcn_mfma_f32_16x16x32_bf16(xf[nh][1], zfh[mi][1], a, 0, 0, 0);
      }

    float d = -1e30f;
#pragma unroll
    for (int mi = 0; mi < 4; ++mi) {
      float mx = fmaxf(fmaxf(acc[mi][0][0], acc[mi][0][1]),
                       fmaxf(acc[mi][0][2], acc[mi][0][3]));
      mx = fmaxf(mx, fmaxf(fmaxf(acc[mi][1][0], acc[mi][1][1]),
                           fmaxf(acc[mi][1][2], acc[mi][1][3])));
      d = fmaxf(d, mx + zq[mi]);
    }
    if (!__any(d > THRESH)) continue;  // ~95% of tiles

    // ---- rare path: refine with cross lo terms, exp2, LDS P, P@alpha ----
    hit = 1;
    bf16x8 xl[2][2];
#pragma unroll
    for (int nh = 0; nh < 2; ++nh)
#pragma unroll
      for (int kh = 0; kh < 2; ++kh)
        xl[nh][kh] = xpl[(nc2 * 4 + nh * 2 + kh) * 64 + lane];

#pragma unroll
    for (int mi = 0; mi < 4; ++mi) {
      bf16x8 zl0 = zplb[mi * 128];
      bf16x8 zl1 = zplb[mi * 128 + 64];
#pragma unroll
      for (int nh = 0; nh < 2; ++nh) {
        f32x4 a = acc[mi][nh];
        a = __builtin_amdgcn_mfma_f32_16x16x32_bf16(xf[nh][0], zl0, a, 0, 0, 0);
        a = __builtin_amdgcn_mfma_f32_16x16x32_bf16(xl[nh][0], zfh[mi][0], a, 0, 0, 0);
        a = __builtin_amdgcn_mfma_f32_16x16x32_bf16(xf[nh][1], zl1, a, 0, 0, 0);
        a = __builtin_amdgcn_mfma_f32_16x16x32_bf16(xl[nh][1], zfh[mi][1], a, 0, 0, 0);
        // P = 2^(S' + zq) — z-factor applied exactly once here
#pragma unroll
        for (int p = 0; p < 2; ++p) {
          float e0 = EXP2(a[2 * p] + zq[mi]);
          float e1 = EXP2(a[2 * p + 1] + zq[mi]);
          unsigned u0 = __float_as_uint(e0) + 0x8000u;
          unsigned u1 = __float_as_uint(e1) + 0x8000u;
          pwbase[(mi * 16) * 20 + nh * 8 + p] = pack_hi16(u1, u0);
        }
      }
    }
    bf16x8 ah = aph[nc2 * 64 + lane];
#pragma unroll
    for (int mi = 0; mi < 4; ++mi) {
      bf16x8 ph = *(const bf16x8*)(prdb + mi * 640);
      oacc[mi] = __builtin_amdgcn_mfma_f32_16x16x32_bf16(ph, ah, oacc[mi], 0, 0, 0);
    }
  }

  if (hit) {  // waves with no rare tile contribute nothing
#pragma unroll
    for (int mi = 0; mi < 4; ++mi)
#pragma unroll
      for (int r = 0; r < 4; ++r) {
        int m = mb + mi * 16 + q * 4 + r;
        atomicAdd(&out[m * 16 + c], oacc[mi][r]);
      }
  }
}

extern "C" void kernel_launch(void* const* d_in, const int* in_sizes, int n_in,
                              void* d_out, int out_size, void* d_ws, size_t ws_size,
                              hipStream_t stream) {
  const float* z = (const float*)d_in[0];
  const float* dataset = (const float*)d_in[1];
  const float* alpha = (const float*)d_in[2];
  float* out = (float*)d_out;
  char* ws = (char*)d_ws;

  bf16x8* xph = (bf16x8*)ws;                       // 12,845,056
  bf16x8* xpl = xph + NC16 * 2 * 64;               // -> 25,690,112
  bf16x8* aph = (bf16x8*)(ws + 25690112);          // 3,211,264 (hi only)
  bf16x8* zph = (bf16x8*)(ws + 32112640);          // 262,144
  bf16x8* zpl = zph + MC16 * 2 * 64;               // -> 32,636,928
  float* xs2 = (float*)(ws + 32636928);            // NPAD floats -> 33,038,336
  float* zs2 = (float*)(ws + 33038336);            // 2048 floats -> 33,046,528

  int total_waves = PREP_WAVES + ZERO_WAVES;       // 9664
  prep_all<<<dim3(total_waves / 4), dim3(256), 0, stream>>>(
      z, dataset, alpha, xph, xpl, zph, zpl, aph, xs2, zs2, out);
  rbf_main<<<dim3(GRID), dim3(256), 0, stream>>>(
      xph, xpl, aph, zph, zpl, xs2, zs2, out);
}